// Round 11
// baseline (291.618 us; speedup 1.0000x reference)
//
#include <hip/hip_runtime.h>
#include <math.h>

#define UNITS 80
#define LATENT 128
#define IN_DIM 256
#define BATCH 8192
#define SEQ 256
#define G 320            // 4*UNITS
#define H2 160           // 2*UNITS
#define ROW_F4 (SEQ * UNITS / 4)       // 5120 f4 per batch row
#define TOT_F4 ((long long)BATCH * ROW_F4)   // 41,943,040

#define TPB 640
#define RPB 16
#define NCB (BATCH / RPB)    // 512 compute blocks (+1 for yc)

#define WB 320               // writer blocks (fill-clone shape)
#define WT 256               // writer threads per block
#define WSTRIDE (WB * WT)    // 81920 f4; 81920 % 5120 == 0

typedef float f4 __attribute__((ext_vector_type(4)));

__device__ __forceinline__ float sigf(float v) {
    return 1.0f / (1.0f + __expf(-v));
}

// ---------------------------------------------------------------------------
// K1: bid 0 -> yc = decode_step(ones);  bid 1..512 -> y0 for 16 rows, store
// only the s=0 slices (320 f4 per block). Body handled by K2.
// ---------------------------------------------------------------------------
__global__ __launch_bounds__(TPB)
void compute_kernel(const float* __restrict__ x,
                    const float* __restrict__ Wl, const float* __restrict__ bl,
                    const float* __restrict__ Kf, const float* __restrict__ bf,
                    const float* __restrict__ Kb, const float* __restrict__ bb,
                    const float* __restrict__ K1, const float* __restrict__ b1,
                    float* __restrict__ yc, float* __restrict__ out) {
    __shared__ float xs[RPB * IN_DIM];     // 16 KB
    __shared__ float lat_s[RPB * LATENT];  // 8 KB
    __shared__ float h_s[RPB * H2];        // 10 KB
    __shared__ float y_s[RPB * UNITS];     // 5 KB

    const int t = threadIdx.x;
    const int bid = blockIdx.x;

    if (bid == 0) {
        // ----- yc path: input all-ones => z = colsum(K) + b -----
        __shared__ float z[2 * G];
        __shared__ float hh[H2];
        {
            const float* K   = (t < G) ? Kf : Kb;
            const float* bia = (t < G) ? bf : bb;
            const int c = (t < G) ? t : t - G;
            float acc = bia[c];
#pragma unroll 8
            for (int l = 0; l < LATENT; ++l) acc += K[l * G + c];
            z[t] = acc;
        }
        __syncthreads();
        if (t < UNITS) {
            hh[t] = sigf(z[240 + t]) * sigf(z[t]) * fmaxf(z[160 + t], 0.f);
        } else if (t >= G && t < G + UNITS) {
            const int u = t - G;
            hh[UNITS + u] = sigf(z[G + 240 + u]) * sigf(z[G + u]) * fmaxf(z[G + 160 + u], 0.f);
        }
        __syncthreads();
        if (t < G) {
            float acc = b1[t];
#pragma unroll 8
            for (int l = 0; l < H2; ++l) acc = fmaf(hh[l], K1[l * G + t], acc);
            z[t] = acc;
        }
        __syncthreads();
        if (t < UNITS) yc[t] = sigf(z[240 + t]) * sigf(z[t]) * fmaxf(z[160 + t], 0.f);
        return;
    }

    const int R0 = (bid - 1) * RPB;

    // stage x (16 rows x 256 f32 = 1024 f4)
    {
        const f4* xg = (const f4*)(x + (size_t)R0 * IN_DIM);
        for (int i = t; i < RPB * IN_DIM / 4; i += TPB) ((f4*)xs)[i] = xg[i];
    }
    __syncthreads();

    // lat = x @ W_lat + b_lat
    for (int i = t; i < RPB * LATENT; i += TPB) {
        const int row = i >> 7, col = i & 127;
        float acc = bl[col];
        const float* xr = xs + row * IN_DIM;
#pragma unroll 8
        for (int l = 0; l < IN_DIM; ++l) acc = fmaf(xr[l], Wl[l * LATENT + col], acc);
        lat_s[i] = acc;
    }
    __syncthreads();

    // fw/bw gates (f dead: c0=0; relu(c)=c since c>=0)
    for (int i = t; i < 2 * RPB * UNITS; i += TPB) {
        const int half = (i >= RPB * UNITS);
        const int j = half ? i - RPB * UNITS : i;
        const int row = j / UNITS;
        const int u = j - row * UNITS;
        const float* K   = half ? Kb : Kf;
        const float* bia = half ? bb : bf;
        float ai = bia[u], ac = bia[160 + u], ao = bia[240 + u];
        const float* lr = lat_s + row * LATENT;
#pragma unroll 4
        for (int k = 0; k < LATENT; ++k) {
            const float lv = lr[k];
            ai = fmaf(lv, K[k * G + u], ai);
            ac = fmaf(lv, K[k * G + 160 + u], ac);
            ao = fmaf(lv, K[k * G + 240 + u], ao);
        }
        h_s[row * H2 + half * UNITS + u] = sigf(ao) * sigf(ai) * fmaxf(ac, 0.f);
    }
    __syncthreads();

    // output LSTM -> y_s
    for (int i = t; i < RPB * UNITS; i += TPB) {
        const int row = i / UNITS;
        const int u = i - row * UNITS;
        float ai = b1[u], ac = b1[160 + u], ao = b1[240 + u];
        const float* hr = h_s + row * H2;
#pragma unroll 4
        for (int k = 0; k < H2; ++k) {
            const float hv = hr[k];
            ai = fmaf(hv, K1[k * G + u], ai);
            ac = fmaf(hv, K1[k * G + 160 + u], ac);
            ao = fmaf(hv, K1[k * G + 240 + u], ao);
        }
        y_s[i] = sigf(ao) * sigf(ai) * fmaxf(ac, 0.f);
    }
    __syncthreads();

    // store s=0 slices: 16 rows x 20 f4
    {
        f4* out4 = (f4*)out;
        const f4* ys4 = (const f4*)y_s;
        for (int i = t; i < RPB * (UNITS / 4); i += TPB) {
            const int row = i / (UNITS / 4);
            const int q = i - row * (UNITS / 4);
            out4[(size_t)(R0 + row) * ROW_F4 + q] = ys4[i];
        }
    }
}

// ---------------------------------------------------------------------------
// K2: fill-clone body writer. Global grid-stride sweep, stride = WSTRIDE f4
// (multiple of ROW_F4), plain f4 stores. Threads at within-row offset < 20
// skip (s=0 is K1's); holes are 320 B = 5 full 64B lines, so every touched
// line is fully covered -> no RFO (proven by rocclr fill's FETCH~0).
// ---------------------------------------------------------------------------
__global__ __launch_bounds__(WT)
void body_kernel(const float* __restrict__ yc, float* __restrict__ out) {
    const int g0 = blockIdx.x * WT + threadIdx.x;     // 0..81919
    const int c = g0 % ROW_F4;                        // within-row f4 offset (const/thread)
    if (c < UNITS / 4) return;                        // s=0 slice: not ours
    const f4 yv = ((const f4*)yc)[c % (UNITS / 4)];
    f4* p = (f4*)out + g0;
    // 41,943,040 / 81,920 = 512 iterations, whole machine sweeps one window
    for (long long g = g0; g < TOT_F4; g += WSTRIDE, p += WSTRIDE)
        *p = yv;
}

extern "C" void kernel_launch(void* const* d_in, const int* in_sizes, int n_in,
                              void* d_out, int out_size, void* d_ws, size_t ws_size,
                              hipStream_t stream) {
    const float* x   = (const float*)d_in[0];
    // d_in[1] = size (scalar, fixed 256)
    const float* Wl  = (const float*)d_in[2];
    const float* bl  = (const float*)d_in[3];
    const float* Kf  = (const float*)d_in[4];
    const float* bf  = (const float*)d_in[5];
    const float* Kb  = (const float*)d_in[6];
    const float* bb  = (const float*)d_in[7];
    const float* K1  = (const float*)d_in[8];
    const float* b1  = (const float*)d_in[9];
    float* out = (float*)d_out;
    float* yc  = (float*)d_ws;   // 80 floats

    compute_kernel<<<NCB + 1, TPB, 0, stream>>>(x, Wl, bl, Kf, bf, Kb, bb, K1, b1, yc, out);
    body_kernel<<<WB, WT, 0, stream>>>(yc, out);
}

// Round 12
// 184.789 us; speedup vs baseline: 1.5781x; 1.5781x over previous
//
#include <hip/hip_runtime.h>
#include <math.h>

#define UNITS 80
#define LATENT 128
#define IN_DIM 256
#define BATCH 8192
#define SEQ 256
#define G 320            // 4*UNITS
#define H2 160           // 2*UNITS
#define ROW_F4 (SEQ * UNITS / 4)   // 5120 f4 per batch row

#define TPB 640          // 10 waves; 640 % 20 == 0 (yc f4 period)
#define RPB 8            // rows per block
#define NBLK (BATCH / RPB)   // 1024 blocks

typedef float f4 __attribute__((ext_vector_type(4)));

__device__ __forceinline__ float sigf(float v) {
    return 1.0f / (1.0f + __expf(-v));
}

// ---------------------------------------------------------------------------
// Single fused kernel. Per block (8 rows):
//   0) in-block yc = decode_step(ones)  (identical in every block; also warms
//      the weight tiles into this XCD's L2)
//   1) x stage -> lat (2 rows/thread) -> gates (4 rows/thread)
//      -> outLSTM (4 rows/thread)   [register tiling: weight loads amortized
//      over rows => machine-wide L2 read traffic ~1.3 GB vs 4.3 GB before]
//   2) store phase: pure nt f4 stream, s=0 slice folded into k=0 iteration.
// ---------------------------------------------------------------------------
__global__ __launch_bounds__(TPB)
void main_kernel(const float* __restrict__ x,
                 const float* __restrict__ Wl, const float* __restrict__ bl,
                 const float* __restrict__ Kf, const float* __restrict__ bf,
                 const float* __restrict__ Kb, const float* __restrict__ bb,
                 const float* __restrict__ K1, const float* __restrict__ b1,
                 float* __restrict__ out) {
    __shared__ float z2[2 * G];           // 2.56 KB (yc gate pre-activations)
    __shared__ float h_c[H2];             // 0.64 KB (yc hidden)
    __shared__ float yc_s[UNITS];         // 0.32 KB
    __shared__ float xs[RPB * IN_DIM];    // 8 KB
    __shared__ float lat_s[RPB * LATENT]; // 4 KB
    __shared__ float h_s[RPB * H2];       // 5 KB
    __shared__ float y_s[RPB * UNITS];    // 2.56 KB

    const int t = threadIdx.x;
    const int R0 = blockIdx.x * RPB;

    // ---- x stage: 8 rows x 256 f32 = 512 f4 ----
    if (t < RPB * IN_DIM / 4)
        ((f4*)xs)[t] = ((const f4*)(x + (size_t)R0 * IN_DIM))[t];

    // ---- yc step A: z = colsum(K) + b (all-ones input), fw|bw in parallel ----
    {
        const float* K   = (t < G) ? Kf : Kb;
        const float* bia = (t < G) ? bf : bb;
        const int c = (t < G) ? t : t - G;
        float acc = bia[c];
#pragma unroll 8
        for (int l = 0; l < LATENT; ++l) acc += K[l * G + c];
        z2[t] = acc;
    }
    __syncthreads();

    // ---- yc step B: h (f gate dead: c0=0; relu(c)=c since c>=0) ----
    if (t < UNITS) {
        h_c[t] = sigf(z2[240 + t]) * sigf(z2[t]) * fmaxf(z2[160 + t], 0.f);
    } else if (t >= G && t < G + UNITS) {
        const int u = t - G;
        h_c[UNITS + u] = sigf(z2[G + 240 + u]) * sigf(z2[G + u]) * fmaxf(z2[G + 160 + u], 0.f);
    }
    __syncthreads();

    // ---- yc step C: z1 = h @ K1 + b1; yc_s = gate(z1) ----
    if (t < G) {
        float acc = b1[t];
#pragma unroll 8
        for (int l = 0; l < H2; ++l) acc = fmaf(h_c[l], K1[l * G + t], acc);
        z2[t] = acc;   // reuse z2[0..319]
    }
    __syncthreads();
    if (t < UNITS) yc_s[t] = sigf(z2[240 + t]) * sigf(z2[t]) * fmaxf(z2[160 + t], 0.f);
    __syncthreads();

    // ---- lat = x @ W_lat + b_lat : col = t&127, 2 rows per thread ----
    if (t < 512) {
        const int col = t & 127;
        const int rg  = t >> 7;            // 0..3 -> rows {2rg, 2rg+1}
        float a0 = bl[col], a1 = a0;
        const float* xr0 = xs + (2 * rg) * IN_DIM;
        const float* xr1 = xr0 + IN_DIM;
#pragma unroll 4
        for (int l = 0; l < IN_DIM; ++l) {
            const float w = Wl[l * LATENT + col];
            a0 = fmaf(xr0[l], w, a0);
            a1 = fmaf(xr1[l], w, a1);
        }
        lat_s[(2 * rg) * LATENT + col] = a0;
        lat_s[(2 * rg + 1) * LATENT + col] = a1;
    }
    __syncthreads();

    // ---- fw/bw gates: t<320: u=t%80, g=t/80: half=g>>1, rows (g&1)*4 .. +3 ----
    if (t < 2 * G / 2) {   // 320
        const int u = t % UNITS;
        const int g = t / UNITS;           // 0..3
        const int half = g >> 1;           // 0=fw, 1=bw
        const int r0 = (g & 1) * 4;
        const float* K   = half ? Kb : Kf;
        const float* bia = half ? bb : bf;
        float ai[4], ac[4], ao[4];
#pragma unroll
        for (int r = 0; r < 4; ++r) { ai[r] = bia[u]; ac[r] = bia[160 + u]; ao[r] = bia[240 + u]; }
#pragma unroll 2
        for (int k = 0; k < LATENT; ++k) {
            const float wi = K[k * G + u];
            const float wc = K[k * G + 160 + u];
            const float wo = K[k * G + 240 + u];
#pragma unroll
            for (int r = 0; r < 4; ++r) {
                const float lv = lat_s[(r0 + r) * LATENT + k];
                ai[r] = fmaf(lv, wi, ai[r]);
                ac[r] = fmaf(lv, wc, ac[r]);
                ao[r] = fmaf(lv, wo, ao[r]);
            }
        }
#pragma unroll
        for (int r = 0; r < 4; ++r)
            h_s[(r0 + r) * H2 + half * UNITS + u] =
                sigf(ao[r]) * sigf(ai[r]) * fmaxf(ac[r], 0.f);
    }
    __syncthreads();

    // ---- output LSTM: t<160: u=t%80, g=t/80: rows g*4 .. g*4+3 ----
    if (t < 2 * UNITS) {   // 160
        const int u = t % UNITS;
        const int g = t / UNITS;           // 0..1
        const int r0 = g * 4;
        float ai[4], ac[4], ao[4];
#pragma unroll
        for (int r = 0; r < 4; ++r) { ai[r] = b1[u]; ac[r] = b1[160 + u]; ao[r] = b1[240 + u]; }
#pragma unroll 2
        for (int k = 0; k < H2; ++k) {
            const float wi = K1[k * G + u];
            const float wc = K1[k * G + 160 + u];
            const float wo = K1[k * G + 240 + u];
#pragma unroll
            for (int r = 0; r < 4; ++r) {
                const float hv = h_s[(r0 + r) * H2 + k];
                ai[r] = fmaf(hv, wi, ai[r]);
                ac[r] = fmaf(hv, wc, ac[r]);
                ao[r] = fmaf(hv, wo, ao[r]);
            }
        }
#pragma unroll
        for (int r = 0; r < 4; ++r)
            y_s[(r0 + r) * UNITS + u] = sigf(ao[r]) * sigf(ai[r]) * fmaxf(ac[r], 0.f);
    }
    __syncthreads();

    // keep stores strictly after all load-uses (no vmcnt interlock)
    __builtin_amdgcn_sched_barrier(0);

    // ---- store phase: 8 rows x 5120 f4, s=0 folded into k=0 ----
    {
        const f4 yv = ((const f4*)yc_s)[t % (UNITS / 4)];   // const per thread
        const f4* ys4 = (const f4*)y_s;                     // [8][20] f4
        f4* out4 = (f4*)out;
#pragma unroll
        for (int r = 0; r < RPB; ++r) {
            f4* rowp = out4 + (size_t)(R0 + r) * ROW_F4;
            const f4 v0 = (t < UNITS / 4) ? ys4[r * (UNITS / 4) + t] : yv;
            __builtin_nontemporal_store(v0, rowp + t);
#pragma unroll
            for (int k = 1; k < ROW_F4 / TPB; ++k)          // k = 1..7
                __builtin_nontemporal_store(yv, rowp + t + k * TPB);
        }
    }
}

extern "C" void kernel_launch(void* const* d_in, const int* in_sizes, int n_in,
                              void* d_out, int out_size, void* d_ws, size_t ws_size,
                              hipStream_t stream) {
    const float* x   = (const float*)d_in[0];
    // d_in[1] = size (scalar, fixed 256)
    const float* Wl  = (const float*)d_in[2];
    const float* bl  = (const float*)d_in[3];
    const float* Kf  = (const float*)d_in[4];
    const float* bf  = (const float*)d_in[5];
    const float* Kb  = (const float*)d_in[6];
    const float* bb  = (const float*)d_in[7];
    const float* K1  = (const float*)d_in[8];
    const float* b1  = (const float*)d_in[9];
    float* out = (float*)d_out;

    main_kernel<<<NBLK, TPB, 0, stream>>>(x, Wl, bl, Kf, bf, Kb, bb, K1, b1, out);
}